// Round 2
// baseline (900.848 us; speedup 1.0000x reference)
//
#include <hip/hip_runtime.h>
#include <cstdint>

// PQ ADC search, MI355X round 2.
// Changes vs R1: codes packed to u8 (4 uint4 loads per row -> deep MLP, ~2
// line-requests/n instead of ~64), scan gathers fully unrolled. Exact fp32
// sequential-m accumulation preserved (bit-identical to reference; rank swaps
// would fail the index check).

#define BQ 32
#define MSUB 64
#define KSUB 256
#define DSUB 4
#define KOUT 64
#define NSAMP 16384
#define TAU_RANK 24        // tau = 24th smallest sampled distance
#define CAP 16384          // candidate storage per query
#define NSORT 4096         // bitonic sort size (>= candidate count w.h.p.)

// ---------------- K0: pack int32 codes -> u8 [n][m] ----------------
__global__ __launch_bounds__(256) void pack_codes(const int4* __restrict__ c4,
                                                  uint4* __restrict__ out,
                                                  long total16) {
    long t = (long)blockIdx.x * 256 + threadIdx.x;   // one thread packs 16 codes
    if (t >= total16) return;
    int4 a = c4[t * 4 + 0], b = c4[t * 4 + 1], c = c4[t * 4 + 2], d = c4[t * 4 + 3];
    uint4 r;
    r.x = (unsigned)(a.x & 255) | ((unsigned)(a.y & 255) << 8) |
          ((unsigned)(a.z & 255) << 16) | ((unsigned)(a.w & 255) << 24);
    r.y = (unsigned)(b.x & 255) | ((unsigned)(b.y & 255) << 8) |
          ((unsigned)(b.z & 255) << 16) | ((unsigned)(b.w & 255) << 24);
    r.z = (unsigned)(c.x & 255) | ((unsigned)(c.y & 255) << 8) |
          ((unsigned)(c.z & 255) << 16) | ((unsigned)(c.w & 255) << 24);
    r.w = (unsigned)(d.x & 255) | ((unsigned)(d.y & 255) << 8) |
          ((unsigned)(d.z & 255) << 16) | ((unsigned)(d.w & 255) << 24);
    out[t] = r;
}

// ---------------- K1: distance table, layout table[m][c][b] (2 MB) ----------------
__global__ __launch_bounds__(256) void build_table(const float* __restrict__ q,
                                                   const float* __restrict__ cw,
                                                   float* __restrict__ table) {
    int tid = blockIdx.x * 256 + threadIdx.x;      // 64*256*32 = 524288
    int b = tid & 31;
    int c = (tid >> 5) & 255;
    int m = tid >> 13;
    const float* qp = q + b * (MSUB * DSUB) + m * DSUB;
    const float* cp = cw + (m * KSUB + c) * DSUB;
    float s = 0.f;
#pragma unroll
    for (int d = 0; d < DSUB; ++d) { float t = qp[d] - cp[d]; s += t * t; }
    table[tid] = s;
}

// ---------------- K2a: distances for sampled n ----------------
__global__ __launch_bounds__(256) void sample_dists(const float* __restrict__ table,
                                                    const int* __restrict__ codes,
                                                    float* __restrict__ samp,
                                                    int stride, int offset) {
    int j = blockIdx.x * 256 + threadIdx.x;        // NSAMP threads
    int n = j * stride + offset;
    const int* crow = codes + (long)n * MSUB;
    float acc[BQ];
#pragma unroll
    for (int b = 0; b < BQ; ++b) acc[b] = 0.f;
    for (int m = 0; m < MSUB; ++m) {
        int c = crow[m];
        const float* t = table + (m * KSUB + c) * BQ;
#pragma unroll
        for (int b = 0; b < BQ; ++b) acc[b] += t[b];
    }
#pragma unroll
    for (int b = 0; b < BQ; ++b) samp[b * NSAMP + j] = acc[b];
}

// ---------------- K2b: per-query threshold via bit-wise binary search ----------------
__global__ __launch_bounds__(256) void find_tau(const float* __restrict__ samp,
                                                float* __restrict__ tau) {
    __shared__ uint32_t sbits[NSAMP];              // 64 KB
    __shared__ int scount;
    int b = blockIdx.x;
    for (int i = threadIdx.x; i < NSAMP; i += 256)
        sbits[i] = __float_as_uint(samp[b * NSAMP + i]);   // positive floats: bits monotone
    __syncthreads();
    uint32_t lo = 0u, hi = 0x7F800000u;
    for (int it = 0; it < 31; ++it) {
        uint32_t mid = (lo + hi) >> 1;
        if (threadIdx.x == 0) scount = 0;
        __syncthreads();
        int c = 0;
        for (int i = threadIdx.x; i < NSAMP; i += 256) c += (sbits[i] <= mid) ? 1 : 0;
        atomicAdd(&scount, c);
        __syncthreads();
        int cnt = scount;
        __syncthreads();
        if (cnt >= TAU_RANK) hi = mid; else lo = mid;
    }
    if (threadIdx.x == 0) tau[b] = __uint_as_float(hi);
}

// ---------------- K3: exact scan + candidate collection (u8 codes) ----------------
// 8 lanes per code row n; lane q4 accumulates queries 4*q4..4*q4+3 as float4.
// All 64 codes loaded up-front as 4x uint4; gathers fully unrolled.
__global__ __launch_bounds__(256) void scan_collect(const float* __restrict__ table,
                                                    const uint4* __restrict__ codes8,
                                                    const float* __restrict__ tau,
                                                    int* __restrict__ cnt,
                                                    int* __restrict__ cidx,
                                                    float* __restrict__ cdist,
                                                    int N) {
    int tid = blockIdx.x * 256 + threadIdx.x;
    int n = tid >> 3;
    if (n >= N) return;
    int q4 = tid & 7;
    const uint4* cr = codes8 + (long)n * 4;
    uint4 c0 = cr[0], c1 = cr[1], c2 = cr[2], c3 = cr[3];
    unsigned cw[16] = {c0.x, c0.y, c0.z, c0.w, c1.x, c1.y, c1.z, c1.w,
                       c2.x, c2.y, c2.z, c2.w, c3.x, c3.y, c3.z, c3.w};
    const char* tb = (const char*)table + q4 * 16;
    float4 acc = {0.f, 0.f, 0.f, 0.f};
#pragma unroll
    for (int w = 0; w < 16; ++w) {
        unsigned word = cw[w];
#pragma unroll
        for (int j = 0; j < 4; ++j) {
            unsigned c = (word >> (8 * j)) & 255u;
            size_t off = (size_t)(w * 4 + j) * (KSUB * BQ * 4) + c * (BQ * 4);
            float4 v = *(const float4*)(tb + off);
            acc.x += v.x; acc.y += v.y; acc.z += v.z; acc.w += v.w;
        }
    }
    float d[4] = {acc.x, acc.y, acc.z, acc.w};
    int b0 = q4 * 4;
#pragma unroll
    for (int j = 0; j < 4; ++j) {
        int b = b0 + j;
        if (d[j] <= tau[b]) {
            int pos = atomicAdd(&cnt[b], 1);
            if (pos < CAP) { cidx[b * CAP + pos] = n; cdist[b * CAP + pos] = d[j]; }
        }
    }
}

// Fallback: same scan reading original int32 codes (if ws too small for u8 copy).
__global__ __launch_bounds__(256) void scan_collect_i32(const float* __restrict__ table,
                                                        const int* __restrict__ codes,
                                                        const float* __restrict__ tau,
                                                        int* __restrict__ cnt,
                                                        int* __restrict__ cidx,
                                                        float* __restrict__ cdist,
                                                        int N) {
    int tid = blockIdx.x * 256 + threadIdx.x;
    int n = tid >> 3;
    if (n >= N) return;
    int q4 = tid & 7;
    const int4* cr = (const int4*)(codes + (long)n * MSUB);
    const char* tb = (const char*)table + q4 * 16;
    float4 acc = {0.f, 0.f, 0.f, 0.f};
#pragma unroll 4
    for (int w = 0; w < 16; ++w) {
        int4 cc = cr[w];
        int cs[4] = {cc.x, cc.y, cc.z, cc.w};
#pragma unroll
        for (int j = 0; j < 4; ++j) {
            size_t off = (size_t)(w * 4 + j) * (KSUB * BQ * 4) + (unsigned)cs[j] * (BQ * 4);
            float4 v = *(const float4*)(tb + off);
            acc.x += v.x; acc.y += v.y; acc.z += v.z; acc.w += v.w;
        }
    }
    float d[4] = {acc.x, acc.y, acc.z, acc.w};
    int b0 = q4 * 4;
#pragma unroll
    for (int j = 0; j < 4; ++j) {
        int b = b0 + j;
        if (d[j] <= tau[b]) {
            int pos = atomicAdd(&cnt[b], 1);
            if (pos < CAP) { cidx[b * CAP + pos] = n; cdist[b * CAP + pos] = d[j]; }
        }
    }
}

// ---------------- K4: per-query exact top-k via bitonic sort ----------------
__global__ __launch_bounds__(256) void final_topk(const int* __restrict__ cnt,
                                                  const int* __restrict__ cidx,
                                                  const float* __restrict__ cdist,
                                                  float* __restrict__ out) {
    __shared__ unsigned long long keys[NSORT];     // 32 KB
    int b = blockIdx.x;
    int m = cnt[b];
    if (m > NSORT) m = NSORT;
    for (int i = threadIdx.x; i < NSORT; i += 256) {
        unsigned long long k;
        if (i < m)
            k = ((unsigned long long)__float_as_uint(cdist[b * CAP + i]) << 32) |
                (unsigned int)cidx[b * CAP + i];
        else
            k = ~0ULL;
        keys[i] = k;
    }
    __syncthreads();
    for (int kk = 2; kk <= NSORT; kk <<= 1) {
        for (int j = kk >> 1; j > 0; j >>= 1) {
            for (int i = threadIdx.x; i < NSORT; i += 256) {
                int ixj = i ^ j;
                if (ixj > i) {
                    unsigned long long a = keys[i], c = keys[ixj];
                    bool up = ((i & kk) == 0);
                    if ((a > c) == up) { keys[i] = c; keys[ixj] = a; }
                }
            }
            __syncthreads();
        }
    }
    for (int r = threadIdx.x; r < KOUT; r += 256) {
        unsigned long long k = keys[r];
        out[b * KOUT + r] = __uint_as_float((unsigned int)(k >> 32));
        out[BQ * KOUT + b * KOUT + r] = (float)(unsigned int)(k & 0xFFFFFFFFu);
    }
}

extern "C" void kernel_launch(void* const* d_in, const int* in_sizes, int n_in,
                              void* d_out, int out_size, void* d_ws, size_t ws_size,
                              hipStream_t stream) {
    const float* querys    = (const float*)d_in[0];
    const float* codewords = (const float*)d_in[1];
    const int*   codes     = (const int*)d_in[2];
    float* out = (float*)d_out;
    int N = in_sizes[2] / MSUB;                    // 1,000,000

    char* ws = (char*)d_ws;
    float* table = (float*)(ws);                           // 2 MB
    float* samp  = (float*)(ws + (2u << 20));              // 2 MB
    float* tau   = (float*)(ws + (4u << 20));              // 128 B
    int*   cnt   = (int*)  (ws + (4u << 20) + 4096);       // 128 B
    int*   cidx  = (int*)  (ws + (4u << 20) + 8192);       // 2 MB
    float* cdist = (float*)(ws + (6u << 20) + 8192);       // 2 MB
    size_t codes8_off = (8u << 20) + 16384;
    uint4* codes8 = (uint4*)(ws + codes8_off);             // N*64 bytes (64 MB)
    bool use_packed = (ws_size >= codes8_off + (size_t)N * MSUB + 1024);

    hipMemsetAsync(cnt, 0, BQ * sizeof(int), stream);

    if (use_packed) {
        long total16 = (long)N * MSUB / 16;                // 4,000,000
        pack_codes<<<(int)((total16 + 255) / 256), 256, 0, stream>>>(
            (const int4*)codes, codes8, total16);
    }

    build_table<<<(MSUB * KSUB * BQ) / 256, 256, 0, stream>>>(querys, codewords, table);

    int stride = N / NSAMP;
    int offset = 17;
    sample_dists<<<NSAMP / 256, 256, 0, stream>>>(table, codes, samp, stride, offset);

    find_tau<<<BQ, 256, 0, stream>>>(samp, tau);

    long total = (long)N * 8;
    int blocks = (int)((total + 255) / 256);
    if (use_packed)
        scan_collect<<<blocks, 256, 0, stream>>>(table, codes8, tau, cnt, cidx, cdist, N);
    else
        scan_collect_i32<<<blocks, 256, 0, stream>>>(table, codes, tau, cnt, cidx, cdist, N);

    final_topk<<<BQ, 256, 0, stream>>>(cnt, cidx, cdist, out);
}